// Round 11
// baseline (146.171 us; speedup 1.0000x reference)
//
#include <hip/hip_runtime.h>
#include <math.h>

#define B_ 2
#define C_ 128
#define H_ 64
#define W_ 64
#define F_ 16
#define U_ 9
#define MD_ 4
#define UV_ 81
#define HW_ (H_*W_)
#define BF_ (B_*F_)

// cvol layout in workspace: cvol[bf][uv][pix], bf = b*F_+f, uv = u*9+v
//   (u = x-shift idx, v = y-shift idx; du=u-4, dv=v-4)
// out0 layout: out0[bf][ch][pix], ch in {flowx, flowy, local_ent, global_ent}

// wave = one image row (64 lanes = x). Each wave: one (y, dv), 3 u's (NG=3),
// 8 f's (f-split by fh). Shifts via per-lane clamped global pointers (no LDS).
// Grid (12, 64, 9): blockIdx.x = b*6+g*2+fh so row-sharing blocks are adjacent.
#define NG_ 3
__global__ __launch_bounds__(64)
void cvol_kernel(const float* __restrict__ ref,
                 const float* __restrict__ tar,
                 const float* __restrict__ pw,
                 float* __restrict__ cvol) {
    const int x    = threadIdx.x;        // lane = pixel x
    const int z12  = blockIdx.x;         // 0..11 = b*6 + g*2 + fh
    const int y    = blockIdx.y;         // row
    const int vidx = blockIdx.z;         // 0..8  y-shift index
    const int b    = z12 / 6;
    const int r6   = z12 - b * 6;
    const int g    = r6 >> 1;            // u-group 0..2
    const int fh   = r6 & 1;             // f-half
    const int U0   = g * NG_;
    const int F0   = fh * 8;
    const int dv   = vidx - MD_;
    const int ys   = y + dv;
    const bool rowv = ((unsigned)ys < (unsigned)H_);
    const int ysc  = rowv ? ys : 0;

    const float* rp = ref + (size_t)b * C_ * HW_ + y * W_ + x;

    // per-lane clamped shifted pointers + validity (hoisted out of c-loop)
    const float* tq[NG_];
    bool vmask[NG_];
#pragma unroll
    for (int i = 0; i < NG_; ++i) {
        int xs = x + U0 + i - MD_;
        vmask[i] = rowv && ((unsigned)xs < (unsigned)W_);
        int xsc = xs < 0 ? 0 : (xs > W_ - 1 ? W_ - 1 : xs);
        tq[i] = tar + (size_t)b * C_ * HW_ + ysc * W_ + xsc;
    }

    float acc[NG_][8];
#pragma unroll
    for (int i = 0; i < NG_; ++i)
#pragma unroll
        for (int f = 0; f < 8; ++f) acc[i][f] = 0.f;

#pragma unroll 4
    for (int c = 0; c < C_; ++c) {
        float rv = rp[(size_t)c * HW_];          // coalesced row load
        float t0 = tq[0][(size_t)c * HW_];       // shifted row loads (1-2 lines)
        float t1 = tq[1][(size_t)c * HW_];
        float t2 = tq[2][(size_t)c * HW_];
        t0 = vmask[0] ? t0 : 0.f;                // zero-pad OOB
        t1 = vmask[1] ? t1 : 0.f;
        t2 = vmask[2] ? t2 : 0.f;
        float p0 = rv * t0; p0 = fmaxf(p0, 0.1f * p0);   // leaky_relu(.,0.1)
        float p1 = rv * t1; p1 = fmaxf(p1, 0.1f * p1);
        float p2 = rv * t2; p2 = fmaxf(p2, 0.1f * p2);
#pragma unroll
        for (int f = 0; f < 8; ++f) {
            float w = pw[(F0 + f) * C_ + c];     // uniform -> scalar K$ load
            acc[0][f] = fmaf(w, p0, acc[0][f]);
            acc[1][f] = fmaf(w, p1, acc[1][f]);
            acc[2][f] = fmaf(w, p2, acc[2][f]);
        }
    }

#pragma unroll
    for (int i = 0; i < NG_; ++i) {
        int plane = (U0 + i) * U_ + vidx;        // uv = u*9 + v
#pragma unroll
        for (int f = 0; f < 8; ++f) {
            float* op = cvol + (((size_t)(b * F_ + F0 + f) * UV_) + plane) * HW_
                      + y * W_ + x;
            *op = acc[i][f];
        }
    }
}

// 4 threads per pixel, each owning a chunk of the 81 uv-planes.
// chunks (ascending uv): j=0 -> [0,21), j=1 -> [21,41), j=2 -> [41,61), j=3 -> [61,81)
__global__ __launch_bounds__(256)
void flowreg_kernel(const float* __restrict__ cvol,
                    float* __restrict__ out0) {
    const int lane = threadIdx.x & 63;
    const int j    = threadIdx.x >> 6;              // 0..3 = uv chunk = wave id
    const int blk  = blockIdx.x;                    // over BF_*HW_/64 = 2048
    const int bf   = blk >> 6;                      // 64 blocks per bf
    const int pix  = (blk & 63) * 64 + lane;

    const float* cp = cvol + (size_t)bf * UV_ * HW_ + pix;

    const int start = (j == 0) ? 0 : (1 + j * 20);
    const int n     = (j == 0) ? 21 : 20;

    float v[21];
#pragma unroll 21
    for (int i = 0; i < n; ++i) v[i] = cp[(size_t)(start + i) * HW_];

    // local argmax (ascending, strict > keeps first occurrence)
    float mv = v[0]; int bi = start;
#pragma unroll 21
    for (int i = 1; i < n; ++i) {
        if (v[i] > mv) { mv = v[i]; bi = start + i; }
    }

    __shared__ float smax[4][64];
    __shared__ int   sidx[4][64];
    smax[j][lane] = mv; sidx[j][lane] = bi;
    __syncthreads();

    // combine chunks ascending -> global first-occurrence argmax (all threads)
    float m = smax[0][lane]; int best = sidx[0][lane];
#pragma unroll
    for (int k = 1; k < 4; ++k) {
        float vv = smax[k][lane];
        if (vv > m) { m = vv; best = sidx[k][lane]; }
    }
    int ub = best / U_;           // x-shift index of argmax
    int vb = best - ub * U_;      // y-shift index

    float S = 0.f, A = 0.f, Sx = 0.f, Sy = 0.f, gS = 0.f, gA = 0.f;
#pragma unroll 21
    for (int i = 0; i < n; ++i) {
        int uv = start + i;
        float d = v[i] - m;
        float z = __expf(d);
        gS += z; gA = fmaf(z, d, gA);
        int u = uv / U_, vy = uv - u * U_;
        int duc = u - ub, dvc = vy - vb;
        bool msk = (duc <= 3) && (duc >= -3) && (dvc <= 3) && (dvc >= -3);
        float zm = msk ? z : 0.f;
        float dm = msk ? d : 0.f;
        S += zm;
        A = fmaf(zm, dm, A);
        Sx = fmaf(zm, (float)(u - MD_), Sx);
        Sy = fmaf(zm, (float)(vy - MD_), Sy);
    }

    __shared__ float sred[6][4][64];
    sred[0][j][lane] = S;  sred[1][j][lane] = A;
    sred[2][j][lane] = Sx; sred[3][j][lane] = Sy;
    sred[4][j][lane] = gS; sred[5][j][lane] = gA;
    __syncthreads();

    if (j == 0) {
        float r[6];
#pragma unroll
        for (int q = 0; q < 6; ++q) {
            float s = sred[q][0][lane];
#pragma unroll
            for (int k = 1; k < 4; ++k) s += sred[q][k][lane];
            r[q] = s;
        }
        float invS = 1.f / r[0];
        float outx = r[2] * invS;
        float outy = r[3] * invS;
        // sum p*log p = A/S - log S  (p = z/S, log p = d - log S)
        float lent = (logf(r[0]) - r[1] * invS) * (1.0f / logf(49.0f));
        float gent = (logf(r[4]) - r[5] / r[4]) * (1.0f / logf(81.0f));

        float* op = out0 + (size_t)bf * 4 * HW_ + pix;
        op[0 * HW_] = outx;
        op[1 * HW_] = outy;
        op[2 * HW_] = lent;
        op[3 * HW_] = gent;
    }
}

// 4 channels per thread: bilinear weights/indices computed once per 4 gathers.
__global__ __launch_bounds__(256)
void warp_kernel(const float* __restrict__ tar,
                 const float* __restrict__ out0,
                 float* __restrict__ warped) {
    int tid = blockIdx.x * 256 + threadIdx.x;   // over B_*(C_/4)*HW_ = 262144
    int pix = tid & (HW_ - 1);
    int t2  = tid >> 12;                        // b*(C_/4)+cg, 0..63
    int b   = t2 >> 5;                          // C_/4 = 32
    int cg  = t2 & 31;
    int x = pix & 63, y = pix >> 6;

    // flow = hypothesis f=0 of out0 for this b
    const float* fbase = out0 + (size_t)(b * F_) * 4 * HW_;
    float fx = fbase[pix];
    float fy = fbase[HW_ + pix];
    float px = (float)x + fx;
    float py = (float)y + fy;

    bool inb = (fabsf(2.0f * px / (float)(W_ - 1) - 1.0f) < 1.0f) &&
               (fabsf(2.0f * py / (float)(H_ - 1) - 1.0f) < 1.0f);

    float x0 = floorf(px), y0 = floorf(py);
    float wx = px - x0,    wy = py - y0;
    int x0i = (int)x0, y0i = (int)y0;

    const float* img = tar + ((size_t)b * C_ + cg * 4) * HW_;

    float acc[4] = {0.f, 0.f, 0.f, 0.f};
    auto tap = [&](int yi, int xi, float wgt) {
        bool v = ((unsigned)xi < (unsigned)W_) && ((unsigned)yi < (unsigned)H_);
        int xc = xi < 0 ? 0 : (xi > W_ - 1 ? W_ - 1 : xi);
        int yc = yi < 0 ? 0 : (yi > H_ - 1 ? H_ - 1 : yi);
        float wg = v ? wgt : 0.f;
        int lin = yc * W_ + xc;
#pragma unroll
        for (int k = 0; k < 4; ++k)
            acc[k] = fmaf(img[(size_t)k * HW_ + lin], wg, acc[k]);
    };

    tap(y0i,     x0i,     (1.f - wx) * (1.f - wy));
    tap(y0i,     x0i + 1, wx * (1.f - wy));
    tap(y0i + 1, x0i,     (1.f - wx) * wy);
    tap(y0i + 1, x0i + 1, wx * wy);

    float* op = warped + ((size_t)b * C_ + cg * 4) * HW_ + pix;
#pragma unroll
    for (int k = 0; k < 4; ++k)
        op[(size_t)k * HW_] = inb ? acc[k] : 0.f;
}

extern "C" void kernel_launch(void* const* d_in, const int* in_sizes, int n_in,
                              void* d_out, int out_size, void* d_ws, size_t ws_size,
                              hipStream_t stream) {
    const float* ref = (const float*)d_in[0];
    const float* tar = (const float*)d_in[1];
    const float* pw  = (const float*)d_in[2];
    float* out0 = (float*)d_out;                       // (B*F, 4, H, W) = 524288 floats
    float* out1 = out0 + (size_t)BF_ * 4 * HW_;        // (B, C, H, W)  = 2097152 floats
    float* cvol = (float*)d_ws;                        // 32*81*4096 floats = 42.5 MB

    dim3 gc(B_ * 6, H_, U_);                           // (b*6+g*2+fh, row, dv)
    cvol_kernel<<<gc, 64, 0, stream>>>(ref, tar, pw, cvol);
    flowreg_kernel<<<(BF_ * HW_) / 64, 256, 0, stream>>>(cvol, out0);
    warp_kernel<<<(B_ * (C_ / 4) * HW_) / 256, 256, 0, stream>>>(tar, out0, out1);
}